// Round 1
// baseline (3848.561 us; speedup 1.0000x reference)
//
#include <hip/hip_runtime.h>
#include <math.h>

// GraphNet: 2x EdgeConv (E=800k, F=H=64) + BN folded/commuted + pooling.
// Structure:
//  k_init  : cast x->bf16, init aggs to -inf, zero stats/pool block
//  k_pass1 : h1a = relu(edgefeat@W1a+b1a), per-channel sum/sumsq over E
//  k_fold1 : s1a,t1a; folded b1b' = b1b + t1a@W1b
//  k_pass2 : recompute h1a, h1b = relu(h1a@(s1a*W1b)+b1b'), stats1b,
//            atomicMax scatter pre-BN h1b into agg1[N,64]
//  k_fold_st: s1b,t1b   (BN commutes with segment_max since gamma>0)
//  k_x1    : x1 = relu(bn1b(agg1) or 0), store f32 + bf16
//  k_pass3 : h2 = relu(edgefeat(x1)@W2+b2), stats2, scatter into agg2
//  k_fold_st: s2,t2
//  k_fuse  : x2=relu(bn2(agg2) or 0); fuse=x1+x2; pool atomics per graph
//  k_out   : [64,128] = concat(graph max, graph mean)

typedef unsigned short u16;
typedef unsigned int   u32;
typedef __bf16 bf16x8 __attribute__((ext_vector_type(8)));
typedef float  f32x4  __attribute__((ext_vector_type(4)));
typedef unsigned short us4 __attribute__((ext_vector_type(4)));

#define EPSBN 1e-5f

// param block layout (floats):
// 0:stS1a[128] 128:stQ1a[128] 256:stS1b[64] 320:stQ1b[64] 384:stS2[64] 448:stQ2[64]
// 512:s1a[128] 640:t1a[128] 768:b1bF[64] 832:s1b[64] 896:t1b[64] 960:s2[64] 1024:t2[64]
// 1088:gmax[4096] 5184:gsum[4096] 9280:cnt[64]  total 9344
#define PB_TOT 9344

__device__ __forceinline__ u32 f2bf1(float f){
    u32 u = __float_as_uint(f);
    return (u + 0x7FFFu + ((u >> 16) & 1u)) >> 16;
}
__device__ __forceinline__ u32 bsub2(u32 xj, u32 xi){
    float jl = __uint_as_float(xj << 16), jh = __uint_as_float(xj & 0xFFFF0000u);
    float il = __uint_as_float(xi << 16), ih = __uint_as_float(xi & 0xFFFF0000u);
    u32 lo = f2bf1(jl - il), hi = f2bf1(jh - ih);
    return lo | (hi << 16);
}
__device__ __forceinline__ void atomicMaxF(float* a, float v){
    if (v >= 0.f) atomicMax((int*)a, __float_as_int(v));
    else          atomicMin((u32*)a, __float_as_uint(v));
}
// XOR swizzle: permutes 8-elem (16B) blocks within a 128-elem row -> ds_read_b128
// across the wave stays at the 8-cycle floor with row pitch 128 (no padding).
__device__ __forceinline__ int swz(int row, int k){
    return row*128 + (k ^ ((row & 7) << 3));
}
__device__ __forceinline__ f32x4 mfma16(bf16x8 a, bf16x8 b, f32x4 c){
    return __builtin_amdgcn_mfma_f32_16x16x32_bf16(a, b, c, 0, 0, 0);
}

// Stage 64 edges (16 per wave; wave stages only its own rows -> no barriers).
// At[edge][0:64]=x[dst], At[edge][64:128]=x[src]-x[dst]  (bf16, swizzled)
__device__ __forceinline__ void stage_edges(u16* At, const u16* __restrict__ xb,
                                            const int* __restrict__ esrc,
                                            const int* __restrict__ edst,
                                            int t, int wave, int lane, int E){
    int eS   = t*64 + wave*16 + (lane >> 2);
    int part = lane & 3;
    int arow = wave*16 + (lane >> 2);
    if (eS < E){
        int sI = esrc[eS], dI = edst[eS];
        const uint4* pi = (const uint4*)(xb + dI*64 + part*16);
        const uint4* pj = (const uint4*)(xb + sI*64 + part*16);
        uint4 xi0 = pi[0], xi1 = pi[1];
        uint4 xj0 = pj[0], xj1 = pj[1];
        *(uint4*)&At[swz(arow, part*16)]     = xi0;
        *(uint4*)&At[swz(arow, part*16+8)]   = xi1;
        uint4 e0, e1;
        e0.x = bsub2(xj0.x, xi0.x); e0.y = bsub2(xj0.y, xi0.y);
        e0.z = bsub2(xj0.z, xi0.z); e0.w = bsub2(xj0.w, xi0.w);
        e1.x = bsub2(xj1.x, xi1.x); e1.y = bsub2(xj1.y, xi1.y);
        e1.z = bsub2(xj1.z, xi1.z); e1.w = bsub2(xj1.w, xi1.w);
        *(uint4*)&At[swz(arow, 64+part*16)]   = e0;
        *(uint4*)&At[swz(arow, 64+part*16+8)] = e1;
    } else {
        uint4 z; z.x = z.y = z.z = z.w = 0u;
        *(uint4*)&At[swz(arow, part*16)]      = z;
        *(uint4*)&At[swz(arow, part*16+8)]    = z;
        *(uint4*)&At[swz(arow, 64+part*16)]   = z;
        *(uint4*)&At[swz(arow, 64+part*16+8)] = z;
    }
}

__global__ void k_init(const float* __restrict__ x, u16* __restrict__ xb,
                       float* __restrict__ agg1, float* __restrict__ agg2,
                       float* __restrict__ pblk, int NF){
    int i = blockIdx.x*256 + threadIdx.x;
    if (i < NF){
        xb[i] = (u16)f2bf1(x[i]);
        agg1[i] = -INFINITY;
        agg2[i] = -INFINITY;
    }
    if (i < PB_TOT){
        pblk[i] = (i >= 1088 && i < 5184) ? -INFINITY : 0.f;
    }
}

__global__ __launch_bounds__(256) void k_pass1(
    const u16* __restrict__ xb, const int* __restrict__ esrc, const int* __restrict__ edst,
    const float* __restrict__ W1a, const float* __restrict__ b1a,
    float* __restrict__ pblk, int E, int nTiles)
{
    __shared__ u16 Wt[128*128];   // Wt[n][k] = W1a[k][n] (bf16, swizzled)
    __shared__ u16 At[64*128];
    int tid = threadIdx.x;
    for (int i = tid; i < 128*128; i += 256){
        int k = i >> 7, n = i & 127;
        Wt[swz(n, k)] = (u16)f2bf1(W1a[i]);
    }
    __syncthreads();
    int lane = tid & 63, wave = tid >> 6;
    int lg = lane >> 4, lr = lane & 15;
    const float4* Bv = (const float4*)b1a;
    float runS[32], runQ[32];
    #pragma unroll
    for (int i = 0; i < 32; i++){ runS[i] = 0.f; runQ[i] = 0.f; }

    for (int t = blockIdx.x; t < nTiles; t += gridDim.x){
        stage_edges(At, xb, esrc, edst, t, wave, lane, E);
        int row = wave*16 + lr;
        bf16x8 bfr[4];
        #pragma unroll
        for (int kt = 0; kt < 4; kt++)
            bfr[kt] = *(const bf16x8*)&At[swz(row, kt*32 + lg*8)];
        bool ev = (t*64 + wave*16 + lr) < E;
        #pragma unroll
        for (int mt = 0; mt < 8; mt++){
            f32x4 acc = {0.f,0.f,0.f,0.f};
            #pragma unroll
            for (int kt = 0; kt < 4; kt++){
                bf16x8 af = *(const bf16x8*)&Wt[swz(mt*16 + lr, kt*32 + lg*8)];
                acc = mfma16(af, bfr[kt], acc);
            }
            if (ev){
                float4 bb = Bv[mt*4 + lg];
                const float* bbp = (const float*)&bb;
                #pragma unroll
                for (int j = 0; j < 4; j++){
                    float h = fmaxf(acc[j] + bbp[j], 0.f);
                    runS[mt*4+j] += h;
                    runQ[mt*4+j] = fmaf(h, h, runQ[mt*4+j]);
                }
            }
        }
    }
    #pragma unroll
    for (int i = 0; i < 32; i++){
        float s = runS[i], q = runQ[i];
        #pragma unroll
        for (int m = 1; m < 16; m <<= 1){ s += __shfl_xor(s, m); q += __shfl_xor(q, m); }
        if (lr == 0){
            int ch = (i >> 2)*16 + lg*4 + (i & 3);
            atomicAdd(&pblk[ch], s);
            atomicAdd(&pblk[128 + ch], q);
        }
    }
}

__global__ void k_fold1(const float* __restrict__ g1a, const float* __restrict__ bt1a,
                        const float* __restrict__ W1b, const float* __restrict__ b1b,
                        float* __restrict__ pblk, float fE)
{
    __shared__ float tS[128];
    int tid = threadIdx.x;
    if (tid < 128){
        float m = pblk[tid] * fE;
        float q = pblk[128 + tid] * fE;
        float v = fmaxf(q - m*m, 0.f);
        float s = g1a[tid] * rsqrtf(v + EPSBN);
        float t = bt1a[tid] - m*s;
        pblk[512 + tid] = s;
        pblk[640 + tid] = t;
        tS[tid] = t;
    }
    __syncthreads();
    if (tid < 64){
        float acc = b1b[tid];
        for (int k = 0; k < 128; k++) acc = fmaf(tS[k], W1b[k*64 + tid], acc);
        pblk[768 + tid] = acc;
    }
}

__global__ __launch_bounds__(256) void k_pass2(
    const u16* __restrict__ xb, const int* __restrict__ esrc, const int* __restrict__ edst,
    const float* __restrict__ W1a, const float* __restrict__ b1a,
    const float* __restrict__ W1b,
    float* __restrict__ pblk, float* __restrict__ agg1, int E, int nTiles)
{
    __shared__ u16 Wt [128*128];  // W1a^T
    __shared__ u16 Wt2[ 64*128];  // (s1a * W1b)^T  (BN1a folded)
    __shared__ u16 At [ 64*128];  // edge feats, then overwritten per-wave with h1a
    int tid = threadIdx.x;
    for (int i = tid; i < 128*128; i += 256){
        int k = i >> 7, n = i & 127;
        Wt[swz(n, k)] = (u16)f2bf1(W1a[i]);
    }
    for (int i = tid; i < 64*128; i += 256){
        int k = i >> 6, n = i & 63;
        Wt2[swz(n, k)] = (u16)f2bf1(W1b[i] * pblk[512 + k]);
    }
    __syncthreads();
    int lane = tid & 63, wave = tid >> 6;
    int lg = lane >> 4, lr = lane & 15;
    const float4* Bv = (const float4*)b1a;
    float runS[16], runQ[16];
    #pragma unroll
    for (int i = 0; i < 16; i++){ runS[i] = 0.f; runQ[i] = 0.f; }

    for (int t = blockIdx.x; t < nTiles; t += gridDim.x){
        stage_edges(At, xb, esrc, edst, t, wave, lane, E);
        int row = wave*16 + lr;
        bf16x8 bfr[4];
        #pragma unroll
        for (int kt = 0; kt < 4; kt++)
            bfr[kt] = *(const bf16x8*)&At[swz(row, kt*32 + lg*8)];
        // GEMM-a: h1a = relu(E@W1a+b1a), write back into At (own rows only)
        #pragma unroll
        for (int mt = 0; mt < 8; mt++){
            f32x4 acc = {0.f,0.f,0.f,0.f};
            #pragma unroll
            for (int kt = 0; kt < 4; kt++){
                bf16x8 af = *(const bf16x8*)&Wt[swz(mt*16 + lr, kt*32 + lg*8)];
                acc = mfma16(af, bfr[kt], acc);
            }
            float4 bb = Bv[mt*4 + lg];
            const float* bbp = (const float*)&bb;
            us4 w;
            #pragma unroll
            for (int j = 0; j < 4; j++)
                w[j] = (u16)f2bf1(fmaxf(acc[j] + bbp[j], 0.f));
            *(us4*)&At[swz(row, mt*16 + lg*4)] = w;
        }
        // GEMM-b: h1b = relu(h1a@W1b'+b1b'); stats + scatter pre-BN (monotone BN)
        bf16x8 br2[4];
        #pragma unroll
        for (int kt = 0; kt < 4; kt++)
            br2[kt] = *(const bf16x8*)&At[swz(row, kt*32 + lg*8)];
        int eV = t*64 + wave*16 + lr;
        bool ev = eV < E;
        int dN = ev ? edst[eV] : 0;
        const float* B2p = &pblk[768];
        #pragma unroll
        for (int mt = 0; mt < 4; mt++){
            f32x4 acc = {0.f,0.f,0.f,0.f};
            #pragma unroll
            for (int kt = 0; kt < 4; kt++){
                bf16x8 af = *(const bf16x8*)&Wt2[swz(mt*16 + lr, kt*32 + lg*8)];
                acc = mfma16(af, br2[kt], acc);
            }
            if (ev){
                #pragma unroll
                for (int j = 0; j < 4; j++){
                    int ch = mt*16 + lg*4 + j;
                    float h = fmaxf(acc[j] + B2p[ch], 0.f);
                    runS[mt*4+j] += h;
                    runQ[mt*4+j] = fmaf(h, h, runQ[mt*4+j]);
                    atomicMaxF(&agg1[dN*64 + ch], h);
                }
            }
        }
    }
    #pragma unroll
    for (int i = 0; i < 16; i++){
        float s = runS[i], q = runQ[i];
        #pragma unroll
        for (int m = 1; m < 16; m <<= 1){ s += __shfl_xor(s, m); q += __shfl_xor(q, m); }
        if (lr == 0){
            int ch = (i >> 2)*16 + lg*4 + (i & 3);
            atomicAdd(&pblk[256 + ch], s);
            atomicAdd(&pblk[320 + ch], q);
        }
    }
}

// generic BN-stat fold for a 64-ch layer
__global__ void k_fold_st(const float* __restrict__ g, const float* __restrict__ bt,
                          float* __restrict__ pblk, float fE, int so, int qo, int os, int ot)
{
    int tid = threadIdx.x;
    if (tid < 64){
        float m = pblk[so + tid] * fE;
        float q = pblk[qo + tid] * fE;
        float v = fmaxf(q - m*m, 0.f);
        float s = g[tid] * rsqrtf(v + EPSBN);
        pblk[os + tid] = s;
        pblk[ot + tid] = bt[tid] - m*s;
    }
}

__global__ void k_x1(const float* __restrict__ agg1, const float* __restrict__ pblk,
                     float* __restrict__ x1f, u16* __restrict__ x1b, int NF)
{
    int i = blockIdx.x*256 + threadIdx.x;
    if (i >= NF) return;
    int c = i & 63;
    float a = agg1[i];
    float v = (a > -INFINITY) ? fmaf(a, pblk[832 + c], pblk[896 + c]) : 0.f;
    v = fmaxf(v, 0.f);
    x1f[i] = v;
    x1b[i] = (u16)f2bf1(v);
}

__global__ __launch_bounds__(256) void k_pass3(
    const u16* __restrict__ x1b, const int* __restrict__ esrc, const int* __restrict__ edst,
    const float* __restrict__ W2, const float* __restrict__ b2,
    float* __restrict__ pblk, float* __restrict__ agg2, int E, int nTiles)
{
    __shared__ u16 Wt[64*128];
    __shared__ u16 At[64*128];
    int tid = threadIdx.x;
    for (int i = tid; i < 64*128; i += 256){
        int k = i >> 6, n = i & 63;
        Wt[swz(n, k)] = (u16)f2bf1(W2[i]);
    }
    __syncthreads();
    int lane = tid & 63, wave = tid >> 6;
    int lg = lane >> 4, lr = lane & 15;
    const float4* Bv = (const float4*)b2;
    float runS[16], runQ[16];
    #pragma unroll
    for (int i = 0; i < 16; i++){ runS[i] = 0.f; runQ[i] = 0.f; }

    for (int t = blockIdx.x; t < nTiles; t += gridDim.x){
        stage_edges(At, x1b, esrc, edst, t, wave, lane, E);
        int row = wave*16 + lr;
        bf16x8 bfr[4];
        #pragma unroll
        for (int kt = 0; kt < 4; kt++)
            bfr[kt] = *(const bf16x8*)&At[swz(row, kt*32 + lg*8)];
        int eV = t*64 + wave*16 + lr;
        bool ev = eV < E;
        int dN = ev ? edst[eV] : 0;
        #pragma unroll
        for (int mt = 0; mt < 4; mt++){
            f32x4 acc = {0.f,0.f,0.f,0.f};
            #pragma unroll
            for (int kt = 0; kt < 4; kt++){
                bf16x8 af = *(const bf16x8*)&Wt[swz(mt*16 + lr, kt*32 + lg*8)];
                acc = mfma16(af, bfr[kt], acc);
            }
            if (ev){
                float4 bb = Bv[mt*4 + lg];
                const float* bbp = (const float*)&bb;
                #pragma unroll
                for (int j = 0; j < 4; j++){
                    int ch = mt*16 + lg*4 + j;
                    float h = fmaxf(acc[j] + bbp[j], 0.f);
                    runS[mt*4+j] += h;
                    runQ[mt*4+j] = fmaf(h, h, runQ[mt*4+j]);
                    atomicMaxF(&agg2[dN*64 + ch], h);
                }
            }
        }
    }
    #pragma unroll
    for (int i = 0; i < 16; i++){
        float s = runS[i], q = runQ[i];
        #pragma unroll
        for (int m = 1; m < 16; m <<= 1){ s += __shfl_xor(s, m); q += __shfl_xor(q, m); }
        if (lr == 0){
            int ch = (i >> 2)*16 + lg*4 + (i & 3);
            atomicAdd(&pblk[384 + ch], s);
            atomicAdd(&pblk[448 + ch], q);
        }
    }
}

__global__ void k_fuse(const float* __restrict__ agg2, const float* __restrict__ x1f,
                       const int* __restrict__ batch, float* __restrict__ pblk, int NF)
{
    int i = blockIdx.x*256 + threadIdx.x;
    if (i >= NF) return;
    int c = i & 63, node = i >> 6;
    float a = agg2[i];
    float v = (a > -INFINITY) ? fmaf(a, pblk[960 + c], pblk[1024 + c]) : 0.f;
    v = fmaxf(v, 0.f);
    float f = x1f[i] + v;
    int g = batch[node];
    atomicMaxF(&pblk[1088 + g*64 + c], f);
    atomicAdd(&pblk[5184 + g*64 + c], f);
    if (c == 0) atomicAdd(&pblk[9280 + g], 1.f);
}

__global__ void k_out(const float* __restrict__ pblk, float* __restrict__ out)
{
    int i = blockIdx.x*256 + threadIdx.x;
    if (i >= 64*128) return;
    int g = i >> 7, c = i & 127;
    float r;
    if (c < 64){
        float m = pblk[1088 + g*64 + c];
        r = (m > -INFINITY) ? m : 0.f;
    } else {
        float s = pblk[5184 + g*64 + (c - 64)];
        float n = pblk[9280 + g];
        r = s / fmaxf(n, 1.f);
    }
    out[i] = r;
}

extern "C" void kernel_launch(void* const* d_in, const int* in_sizes, int n_in,
                              void* d_out, int out_size, void* d_ws, size_t ws_size,
                              hipStream_t stream)
{
    const float* x    = (const float*)d_in[0];
    const int*   ei   = (const int*)  d_in[1];
    const int*   batch= (const int*)  d_in[2];
    const float* W1a  = (const float*)d_in[3];
    const float* b1a  = (const float*)d_in[4];
    const float* g1a  = (const float*)d_in[5];
    const float* bt1a = (const float*)d_in[6];
    const float* W1b  = (const float*)d_in[7];
    const float* b1b  = (const float*)d_in[8];
    const float* g1b  = (const float*)d_in[9];
    const float* bt1b = (const float*)d_in[10];
    const float* W2   = (const float*)d_in[11];
    const float* b2   = (const float*)d_in[12];
    const float* g2   = (const float*)d_in[13];
    const float* bt2  = (const float*)d_in[14];

    int N  = in_sizes[0] / 64;
    int E  = in_sizes[1] / 2;
    int NF = N * 64;

    char* ws = (char*)d_ws;
    size_t off = 0;
    auto alloc = [&](size_t bytes){ size_t o = off; off += (bytes + 255) & ~(size_t)255; return o; };
    u16*   xb   = (u16*)  (ws + alloc((size_t)NF*2));
    u16*   x1b  = (u16*)  (ws + alloc((size_t)NF*2));
    float* x1f  = (float*)(ws + alloc((size_t)NF*4));
    float* agg1 = (float*)(ws + alloc((size_t)NF*4));
    float* agg2 = (float*)(ws + alloc((size_t)NF*4));
    float* pblk = (float*)(ws + alloc((size_t)PB_TOT*4));
    (void)ws_size;

    const int* esrc = ei;
    const int* edst = ei + E;
    int nTiles = (E + 63) / 64;
    int gPass  = nTiles < 2048 ? nTiles : 2048;
    int gElem  = (NF + 255) / 256;
    float fE   = 1.f / (float)E;

    k_init <<<gElem, 256, 0, stream>>>(x, xb, agg1, agg2, pblk, NF);
    k_pass1<<<gPass, 256, 0, stream>>>(xb, esrc, edst, W1a, b1a, pblk, E, nTiles);
    k_fold1<<<1, 128, 0, stream>>>(g1a, bt1a, W1b, b1b, pblk, fE);
    k_pass2<<<gPass, 256, 0, stream>>>(xb, esrc, edst, W1a, b1a, W1b, pblk, agg1, E, nTiles);
    k_fold_st<<<1, 64, 0, stream>>>(g1b, bt1b, pblk, fE, 256, 320, 832, 896);
    k_x1   <<<gElem, 256, 0, stream>>>(agg1, pblk, x1f, x1b, NF);
    k_pass3<<<gPass, 256, 0, stream>>>(x1b, esrc, edst, W2, b2, pblk, agg2, E, nTiles);
    k_fold_st<<<1, 64, 0, stream>>>(g2, bt2, pblk, fE, 384, 448, 960, 1024);
    k_fuse <<<gElem, 256, 0, stream>>>(agg2, x1f, batch, pblk, NF);
    k_out  <<<32, 256, 0, stream>>>(pblk, (float*)d_out);
}

// Round 4
// 2863.309 us; speedup vs baseline: 1.3441x; 1.3441x over previous
//
#include <hip/hip_runtime.h>
#include <math.h>

// GraphNet: 2x EdgeConv (E=800k, F=H=64) + BN folded/commuted + pooling.
// R4: R3 design; BUGFIX: segmented-max masks computed with UNCONDITIONAL
// __shfl_down (R2/R3 had the shfl inside a short-circuit && -> exec-masked
// lanes -> ds_bpermute reads from inactive lanes -> garbage merge masks).

typedef unsigned short u16;
typedef unsigned int   u32;
typedef __bf16 bf16x8 __attribute__((ext_vector_type(8)));
typedef float  f32x4  __attribute__((ext_vector_type(4)));
typedef unsigned short us4 __attribute__((ext_vector_type(4)));

#define EPSBN 1e-5f

// param block layout (floats):
// 0:stS1a[128] 128:stQ1a[128] 256:stS1b[64] 320:stQ1b[64] 384:stS2[64] 448:stQ2[64]
// 512:s1a[128] 640:t1a[128] 768:b1bF[64] 832:s1b[64] 896:t1b[64] 960:s2[64] 1024:t2[64]
// 1088:gmax[4096] 5184:gsum[4096] 9280:cnt[64]  total 9344
#define PB_TOT 9344

__device__ __forceinline__ u32 f2bf1(float f){
    u32 u = __float_as_uint(f);
    return (u + 0x7FFFu + ((u >> 16) & 1u)) >> 16;
}
__device__ __forceinline__ float bf2f(u16 b){
    return __uint_as_float(((u32)b) << 16);
}
__device__ __forceinline__ u32 bsub2(u32 xj, u32 xi){
    float jl = __uint_as_float(xj << 16), jh = __uint_as_float(xj & 0xFFFF0000u);
    float il = __uint_as_float(xi << 16), ih = __uint_as_float(xi & 0xFFFF0000u);
    u32 lo = f2bf1(jl - il), hi = f2bf1(jh - ih);
    return lo | (hi << 16);
}
__device__ __forceinline__ void atomicMaxF(float* a, float v){
    if (v >= 0.f) atomicMax((int*)a, __float_as_int(v));
    else          atomicMin((u32*)a, __float_as_uint(v));
}
// XOR swizzle: permutes 8-elem (16B) blocks within a 128-elem row -> ds_read_b128
__device__ __forceinline__ int swz(int row, int k){
    return row*128 + (k ^ ((row & 7) << 3));
}
__device__ __forceinline__ f32x4 mfma16(bf16x8 a, bf16x8 b, f32x4 c){
    return __builtin_amdgcn_mfma_f32_16x16x32_bf16(a, b, c, 0, 0, 0);
}

// Segment-run merge masks over a 16-lane group. ALL shuffles unconditional
// (straight-line, all lanes active); guards applied after.
struct SegMasks { bool head, m1, m2, m4, m8; };
__device__ __forceinline__ SegMasks seg_masks(int dL, int lr){
    int dUp = __shfl_up(dL, 1, 16);
    int d1  = __shfl_down(dL, 1, 16);
    int d2  = __shfl_down(dL, 2, 16);
    int d4  = __shfl_down(dL, 4, 16);
    int d8  = __shfl_down(dL, 8, 16);
    SegMasks s;
    s.head = (lr == 0) || (dUp != dL);
    s.m1 = (lr + 1 < 16) && (d1 == dL);
    s.m2 = (lr + 2 < 16) && (d2 == dL);
    s.m4 = (lr + 4 < 16) && (d4 == dL);
    s.m8 = (lr + 8 < 16) && (d8 == dL);
    return s;
}
__device__ __forceinline__ float seg_max(float v, const SegMasks& s){
    float t1 = __shfl_down(v, 1, 16); if (s.m1) v = fmaxf(v, t1);
    float t2 = __shfl_down(v, 2, 16); if (s.m2) v = fmaxf(v, t2);
    float t4 = __shfl_down(v, 4, 16); if (s.m4) v = fmaxf(v, t4);
    float t8 = __shfl_down(v, 8, 16); if (s.m8) v = fmaxf(v, t8);
    return v;
}

// Stage 64 edges (16 per wave; wave stages only its own rows -> no barriers).
// Edge order is the dst-sorted permutation eord.
__device__ __forceinline__ void stage_edges(u16* At, const u16* __restrict__ xb,
                                            const int* __restrict__ eord,
                                            const int* __restrict__ esrc,
                                            const int* __restrict__ edst,
                                            int t, int wave, int lane, int E){
    int eS   = t*64 + wave*16 + (lane >> 2);
    int part = lane & 3;
    int arow = wave*16 + (lane >> 2);
    if (eS < E){
        int e  = eord[eS];
        int sI = esrc[e], dI = edst[e];
        const uint4* pi = (const uint4*)(xb + dI*64 + part*16);
        const uint4* pj = (const uint4*)(xb + sI*64 + part*16);
        uint4 xi0 = pi[0], xi1 = pi[1];
        uint4 xj0 = pj[0], xj1 = pj[1];
        *(uint4*)&At[swz(arow, part*16)]     = xi0;
        *(uint4*)&At[swz(arow, part*16+8)]   = xi1;
        uint4 e0, e1;
        e0.x = bsub2(xj0.x, xi0.x); e0.y = bsub2(xj0.y, xi0.y);
        e0.z = bsub2(xj0.z, xi0.z); e0.w = bsub2(xj0.w, xi0.w);
        e1.x = bsub2(xj1.x, xi1.x); e1.y = bsub2(xj1.y, xi1.y);
        e1.z = bsub2(xj1.z, xi1.z); e1.w = bsub2(xj1.w, xi1.w);
        *(uint4*)&At[swz(arow, 64+part*16)]   = e0;
        *(uint4*)&At[swz(arow, 64+part*16+8)] = e1;
    } else {
        uint4 z; z.x = z.y = z.z = z.w = 0u;
        *(uint4*)&At[swz(arow, part*16)]      = z;
        *(uint4*)&At[swz(arow, part*16+8)]    = z;
        *(uint4*)&At[swz(arow, 64+part*16)]   = z;
        *(uint4*)&At[swz(arow, 64+part*16+8)] = z;
    }
}

__global__ void k_init(const float* __restrict__ x, u16* __restrict__ xb,
                       float* __restrict__ agg,
                       float* __restrict__ pblk, int* __restrict__ deg,
                       int NF, int N){
    int i = blockIdx.x*256 + threadIdx.x;
    if (i < NF){
        xb[i] = (u16)f2bf1(x[i]);
        agg[i] = -INFINITY;
    }
    if (i < N) deg[i] = 0;
    if (i < PB_TOT){
        pblk[i] = (i >= 1088 && i < 5184) ? -INFINITY : 0.f;
    }
}

__global__ void k_hist(const int* __restrict__ edst, int* __restrict__ deg, int E){
    int e = blockIdx.x*256 + threadIdx.x;
    if (e < E) atomicAdd(&deg[edst[e]], 1);
}

// single-block exclusive scan of deg[0..N) -> cursor[0..N)
__global__ __launch_bounds__(1024) void k_scan(const int* __restrict__ deg,
                                               int* __restrict__ cursor, int N){
    __shared__ int buf[1024];
    __shared__ int carry;
    int tid = threadIdx.x;
    if (tid == 0) carry = 0;
    __syncthreads();
    for (int base = 0; base < N; base += 1024){
        int i = base + tid;
        int v = (i < N) ? deg[i] : 0;
        buf[tid] = v;
        __syncthreads();
        #pragma unroll
        for (int s = 1; s < 1024; s <<= 1){
            int a = (tid >= s) ? buf[tid - s] : 0;
            __syncthreads();
            buf[tid] += a;
            __syncthreads();
        }
        int inc = buf[tid] + carry;
        if (i < N) cursor[i] = inc - v;
        __syncthreads();
        if (tid == 1023) carry = inc;
        __syncthreads();
    }
}

__global__ void k_scatter(const int* __restrict__ edst, int* __restrict__ cursor,
                          int* __restrict__ eord, int E){
    int e = blockIdx.x*256 + threadIdx.x;
    if (e < E){
        int pos = atomicAdd(&cursor[edst[e]], 1);
        eord[pos] = e;
    }
}

__global__ __launch_bounds__(256) void k_pass1(
    const u16* __restrict__ xb, const int* __restrict__ eord,
    const int* __restrict__ esrc, const int* __restrict__ edst,
    const float* __restrict__ W1a, const float* __restrict__ b1a,
    float* __restrict__ pblk, int E, int nTiles)
{
    __shared__ u16 Wt[128*128];   // Wt[n][k] = W1a[k][n] (bf16, swizzled)
    __shared__ u16 At[64*128];
    int tid = threadIdx.x;
    for (int i = tid; i < 128*128; i += 256){
        int k = i >> 7, n = i & 127;
        Wt[swz(n, k)] = (u16)f2bf1(W1a[i]);
    }
    __syncthreads();
    int lane = tid & 63, wave = tid >> 6;
    int lg = lane >> 4, lr = lane & 15;
    const float4* Bv = (const float4*)b1a;
    float runS[32], runQ[32];
    #pragma unroll
    for (int i = 0; i < 32; i++){ runS[i] = 0.f; runQ[i] = 0.f; }

    for (int t = blockIdx.x; t < nTiles; t += gridDim.x){
        stage_edges(At, xb, eord, esrc, edst, t, wave, lane, E);
        int row = wave*16 + lr;
        bf16x8 bfr[4];
        #pragma unroll
        for (int kt = 0; kt < 4; kt++)
            bfr[kt] = *(const bf16x8*)&At[swz(row, kt*32 + lg*8)];
        bool ev = (t*64 + wave*16 + lr) < E;
        #pragma unroll
        for (int mt = 0; mt < 8; mt++){
            f32x4 acc = {0.f,0.f,0.f,0.f};
            #pragma unroll
            for (int kt = 0; kt < 4; kt++){
                bf16x8 af = *(const bf16x8*)&Wt[swz(mt*16 + lr, kt*32 + lg*8)];
                acc = mfma16(af, bfr[kt], acc);
            }
            if (ev){
                float4 bb = Bv[mt*4 + lg];
                const float* bbp = (const float*)&bb;
                #pragma unroll
                for (int j = 0; j < 4; j++){
                    float h = fmaxf(acc[j] + bbp[j], 0.f);
                    runS[mt*4+j] += h;
                    runQ[mt*4+j] = fmaf(h, h, runQ[mt*4+j]);
                }
            }
        }
    }
    #pragma unroll
    for (int i = 0; i < 32; i++){
        float s = runS[i], q = runQ[i];
        #pragma unroll
        for (int m = 1; m < 16; m <<= 1){ s += __shfl_xor(s, m); q += __shfl_xor(q, m); }
        if (lr == 0){
            int ch = (i >> 2)*16 + lg*4 + (i & 3);
            atomicAdd(&pblk[ch], s);
            atomicAdd(&pblk[128 + ch], q);
        }
    }
}

__global__ void k_fold1(const float* __restrict__ g1a, const float* __restrict__ bt1a,
                        const float* __restrict__ W1b, const float* __restrict__ b1b,
                        float* __restrict__ pblk, float fE)
{
    __shared__ float tS[128];
    int tid = threadIdx.x;
    if (tid < 128){
        float m = pblk[tid] * fE;
        float q = pblk[128 + tid] * fE;
        float v = fmaxf(q - m*m, 0.f);
        float s = g1a[tid] * rsqrtf(v + EPSBN);
        float t = bt1a[tid] - m*s;
        pblk[512 + tid] = s;
        pblk[640 + tid] = t;
        tS[tid] = t;
    }
    __syncthreads();
    if (tid < 64){
        float acc = b1b[tid];
        for (int k = 0; k < 128; k++) acc = fmaf(tS[k], W1b[k*64 + tid], acc);
        pblk[768 + tid] = acc;
    }
}

__global__ __launch_bounds__(256) void k_pass2(
    const u16* __restrict__ xb, const int* __restrict__ eord,
    const int* __restrict__ esrc, const int* __restrict__ edst,
    const float* __restrict__ W1a, const float* __restrict__ b1a,
    const float* __restrict__ W1b,
    float* __restrict__ pblk, float* __restrict__ agg, int E, int nTiles)
{
    __shared__ u16 Wt [128*128];  // W1a^T
    __shared__ u16 Wt2[ 64*128];  // (s1a * W1b)^T  (BN1a folded)
    __shared__ u16 At [ 64*128];
    int tid = threadIdx.x;
    for (int i = tid; i < 128*128; i += 256){
        int k = i >> 7, n = i & 127;
        Wt[swz(n, k)] = (u16)f2bf1(W1a[i]);
    }
    for (int i = tid; i < 64*128; i += 256){
        int k = i >> 6, n = i & 63;
        Wt2[swz(n, k)] = (u16)f2bf1(W1b[i] * pblk[512 + k]);
    }
    __syncthreads();
    int lane = tid & 63, wave = tid >> 6;
    int lg = lane >> 4, lr = lane & 15;
    const float4* Bv = (const float4*)b1a;
    float runS[16], runQ[16];
    #pragma unroll
    for (int i = 0; i < 16; i++){ runS[i] = 0.f; runQ[i] = 0.f; }

    for (int t = blockIdx.x; t < nTiles; t += gridDim.x){
        stage_edges(At, xb, eord, esrc, edst, t, wave, lane, E);
        int row = wave*16 + lr;
        bf16x8 bfr[4];
        #pragma unroll
        for (int kt = 0; kt < 4; kt++)
            bfr[kt] = *(const bf16x8*)&At[swz(row, kt*32 + lg*8)];
        // GEMM-a: h1a = relu(E@W1a+b1a), write back into At (own rows only)
        #pragma unroll
        for (int mt = 0; mt < 8; mt++){
            f32x4 acc = {0.f,0.f,0.f,0.f};
            #pragma unroll
            for (int kt = 0; kt < 4; kt++){
                bf16x8 af = *(const bf16x8*)&Wt[swz(mt*16 + lr, kt*32 + lg*8)];
                acc = mfma16(af, bfr[kt], acc);
            }
            float4 bb = Bv[mt*4 + lg];
            const float* bbp = (const float*)&bb;
            us4 w;
            #pragma unroll
            for (int j = 0; j < 4; j++)
                w[j] = (u16)f2bf1(fmaxf(acc[j] + bbp[j], 0.f));
            *(us4*)&At[swz(row, mt*16 + lg*4)] = w;
        }
        // GEMM-b + segmented-max scatter
        bf16x8 br2[4];
        #pragma unroll
        for (int kt = 0; kt < 4; kt++)
            br2[kt] = *(const bf16x8*)&At[swz(row, kt*32 + lg*8)];
        int eV = t*64 + wave*16 + lr;
        bool ev = eV < E;
        int dL = ev ? edst[eord[eV]] : -2;
        SegMasks sm = seg_masks(dL, lr);
        const float* B2p = &pblk[768];
        #pragma unroll
        for (int mt = 0; mt < 4; mt++){
            f32x4 acc = {0.f,0.f,0.f,0.f};
            #pragma unroll
            for (int kt = 0; kt < 4; kt++){
                bf16x8 af = *(const bf16x8*)&Wt2[swz(mt*16 + lr, kt*32 + lg*8)];
                acc = mfma16(af, br2[kt], acc);
            }
            #pragma unroll
            for (int j = 0; j < 4; j++){
                int ch = mt*16 + lg*4 + j;
                float h = fmaxf(acc[j] + B2p[ch], 0.f);
                if (ev){
                    runS[mt*4+j] += h;
                    runQ[mt*4+j] = fmaf(h, h, runQ[mt*4+j]);
                }
                float v = seg_max(h, sm);
                if (sm.head && ev) atomicMaxF(&agg[dL*64 + ch], v);
            }
        }
    }
    #pragma unroll
    for (int i = 0; i < 16; i++){
        float s = runS[i], q = runQ[i];
        #pragma unroll
        for (int m = 1; m < 16; m <<= 1){ s += __shfl_xor(s, m); q += __shfl_xor(q, m); }
        if (lr == 0){
            int ch = (i >> 2)*16 + lg*4 + (i & 3);
            atomicAdd(&pblk[256 + ch], s);
            atomicAdd(&pblk[320 + ch], q);
        }
    }
}

// generic BN-stat fold for a 64-ch layer
__global__ void k_fold_st(const float* __restrict__ g, const float* __restrict__ bt,
                          float* __restrict__ pblk, float fE, int so, int qo, int os, int ot)
{
    int tid = threadIdx.x;
    if (tid < 64){
        float m = pblk[so + tid] * fE;
        float q = pblk[qo + tid] * fE;
        float v = fmaxf(q - m*m, 0.f);
        float s = g[tid] * rsqrtf(v + EPSBN);
        pblk[os + tid] = s;
        pblk[ot + tid] = bt[tid] - m*s;
    }
}

// x1 = relu(bn1b(agg) or 0) -> x1b (bf16); reset agg to -inf for pass3 reuse
__global__ void k_x1(float* __restrict__ agg, const float* __restrict__ pblk,
                     u16* __restrict__ x1b, int NF)
{
    int i = blockIdx.x*256 + threadIdx.x;
    if (i >= NF) return;
    int c = i & 63;
    float a = agg[i];
    float v = (a > -INFINITY) ? fmaf(a, pblk[832 + c], pblk[896 + c]) : 0.f;
    v = fmaxf(v, 0.f);
    x1b[i] = (u16)f2bf1(v);
    agg[i] = -INFINITY;
}

__global__ __launch_bounds__(256) void k_pass3(
    const u16* __restrict__ x1b, const int* __restrict__ eord,
    const int* __restrict__ esrc, const int* __restrict__ edst,
    const float* __restrict__ W2, const float* __restrict__ b2,
    float* __restrict__ pblk, float* __restrict__ agg, int E, int nTiles)
{
    __shared__ u16 Wt[64*128];
    __shared__ u16 At[64*128];
    int tid = threadIdx.x;
    for (int i = tid; i < 64*128; i += 256){
        int k = i >> 6, n = i & 63;
        Wt[swz(n, k)] = (u16)f2bf1(W2[i]);
    }
    __syncthreads();
    int lane = tid & 63, wave = tid >> 6;
    int lg = lane >> 4, lr = lane & 15;
    const float4* Bv = (const float4*)b2;
    float runS[16], runQ[16];
    #pragma unroll
    for (int i = 0; i < 16; i++){ runS[i] = 0.f; runQ[i] = 0.f; }

    for (int t = blockIdx.x; t < nTiles; t += gridDim.x){
        stage_edges(At, x1b, eord, esrc, edst, t, wave, lane, E);
        int row = wave*16 + lr;
        bf16x8 bfr[4];
        #pragma unroll
        for (int kt = 0; kt < 4; kt++)
            bfr[kt] = *(const bf16x8*)&At[swz(row, kt*32 + lg*8)];
        int eV = t*64 + wave*16 + lr;
        bool ev = eV < E;
        int dL = ev ? edst[eord[eV]] : -2;
        SegMasks sm = seg_masks(dL, lr);
        #pragma unroll
        for (int mt = 0; mt < 4; mt++){
            f32x4 acc = {0.f,0.f,0.f,0.f};
            #pragma unroll
            for (int kt = 0; kt < 4; kt++){
                bf16x8 af = *(const bf16x8*)&Wt[swz(mt*16 + lr, kt*32 + lg*8)];
                acc = mfma16(af, bfr[kt], acc);
            }
            float4 bb = Bv[mt*4 + lg];
            const float* bbp = (const float*)&bb;
            #pragma unroll
            for (int j = 0; j < 4; j++){
                int ch = mt*16 + lg*4 + j;
                float h = fmaxf(acc[j] + bbp[j], 0.f);
                if (ev){
                    runS[mt*4+j] += h;
                    runQ[mt*4+j] = fmaf(h, h, runQ[mt*4+j]);
                }
                float v = seg_max(h, sm);
                if (sm.head && ev) atomicMaxF(&agg[dL*64 + ch], v);
            }
        }
    }
    #pragma unroll
    for (int i = 0; i < 16; i++){
        float s = runS[i], q = runQ[i];
        #pragma unroll
        for (int m = 1; m < 16; m <<= 1){ s += __shfl_xor(s, m); q += __shfl_xor(q, m); }
        if (lr == 0){
            int ch = (i >> 2)*16 + lg*4 + (i & 3);
            atomicAdd(&pblk[384 + ch], s);
            atomicAdd(&pblk[448 + ch], q);
        }
    }
}

// 256 threads = 4 groups x 64 channels; each group serially accumulates 32
// sorted nodes, flushing per graph-run -> ~200k atomics total.
#define FUSE_NODES 128
__global__ __launch_bounds__(256) void k_fuse(const float* __restrict__ agg,
                                              const u16* __restrict__ x1b,
                                              const int* __restrict__ batch,
                                              float* __restrict__ pblk, int N)
{
    int c = threadIdx.x & 63, r = threadIdx.x >> 6;
    int n0 = blockIdx.x*FUSE_NODES + r*(FUSE_NODES/4);
    if (n0 >= N) return;
    int n1 = n0 + FUSE_NODES/4; if (n1 > N) n1 = N;
    float s2c = pblk[960 + c], t2c = pblk[1024 + c];
    float gm = -INFINITY, gs = 0.f;
    int cur = batch[n0], cnt0 = 0;
    for (int n = n0; n < n1; ++n){
        int g = batch[n];
        if (g != cur){
            atomicMaxF(&pblk[1088 + cur*64 + c], gm);
            atomicAdd(&pblk[5184 + cur*64 + c], gs);
            if (c == 0) atomicAdd(&pblk[9280 + cur], (float)cnt0);
            gm = -INFINITY; gs = 0.f; cnt0 = 0; cur = g;
        }
        float a = agg[n*64 + c];
        float v = (a > -INFINITY) ? fmaf(a, s2c, t2c) : 0.f;
        v = fmaxf(v, 0.f);
        float f = bf2f(x1b[n*64 + c]) + v;
        gm = fmaxf(gm, f); gs += f; cnt0++;
    }
    atomicMaxF(&pblk[1088 + cur*64 + c], gm);
    atomicAdd(&pblk[5184 + cur*64 + c], gs);
    if (c == 0) atomicAdd(&pblk[9280 + cur], (float)cnt0);
}

__global__ void k_out(const float* __restrict__ pblk, float* __restrict__ out)
{
    int i = blockIdx.x*256 + threadIdx.x;
    if (i >= 64*128) return;
    int g = i >> 7, c = i & 127;
    float r;
    if (c < 64){
        float m = pblk[1088 + g*64 + c];
        r = (m > -INFINITY) ? m : 0.f;
    } else {
        float s = pblk[5184 + g*64 + (c - 64)];
        float n = pblk[9280 + g];
        r = s / fmaxf(n, 1.f);
    }
    out[i] = r;
}

extern "C" void kernel_launch(void* const* d_in, const int* in_sizes, int n_in,
                              void* d_out, int out_size, void* d_ws, size_t ws_size,
                              hipStream_t stream)
{
    const float* x    = (const float*)d_in[0];
    const int*   ei   = (const int*)  d_in[1];
    const int*   batch= (const int*)  d_in[2];
    const float* W1a  = (const float*)d_in[3];
    const float* b1a  = (const float*)d_in[4];
    const float* g1a  = (const float*)d_in[5];
    const float* bt1a = (const float*)d_in[6];
    const float* W1b  = (const float*)d_in[7];
    const float* b1b  = (const float*)d_in[8];
    const float* g1b  = (const float*)d_in[9];
    const float* bt1b = (const float*)d_in[10];
    const float* W2   = (const float*)d_in[11];
    const float* b2   = (const float*)d_in[12];
    const float* g2   = (const float*)d_in[13];
    const float* bt2  = (const float*)d_in[14];

    int N  = in_sizes[0] / 64;
    int E  = in_sizes[1] / 2;
    int NF = N * 64;

    char* ws = (char*)d_ws;
    size_t off = 0;
    auto alloc = [&](size_t bytes){ size_t o = off; off += (bytes + 255) & ~(size_t)255; return o; };
    u16*   xb    = (u16*)  (ws + alloc((size_t)NF*2));
    u16*   x1b   = (u16*)  (ws + alloc((size_t)NF*2));
    float* agg   = (float*)(ws + alloc((size_t)NF*4));
    float* pblk  = (float*)(ws + alloc((size_t)PB_TOT*4));
    int*   deg   = (int*)  (ws + alloc((size_t)N*4));
    int*   cursor= (int*)  (ws + alloc((size_t)N*4));
    int*   eord  = (int*)  (ws + alloc((size_t)E*4));
    (void)ws_size;

    const int* esrc = ei;
    const int* edst = ei + E;
    int nTiles = (E + 63) / 64;
    int gPass  = nTiles < 2048 ? nTiles : 2048;
    int gElem  = (NF + 255) / 256;
    int gEdge  = (E + 255) / 256;
    float fE   = 1.f / (float)E;

    k_init   <<<gElem, 256, 0, stream>>>(x, xb, agg, pblk, deg, NF, N);
    k_hist   <<<gEdge, 256, 0, stream>>>(edst, deg, E);
    k_scan   <<<1, 1024, 0, stream>>>(deg, cursor, N);
    k_scatter<<<gEdge, 256, 0, stream>>>(edst, cursor, eord, E);
    k_pass1  <<<gPass, 256, 0, stream>>>(xb, eord, esrc, edst, W1a, b1a, pblk, E, nTiles);
    k_fold1  <<<1, 128, 0, stream>>>(g1a, bt1a, W1b, b1b, pblk, fE);
    k_pass2  <<<gPass, 256, 0, stream>>>(xb, eord, esrc, edst, W1a, b1a, W1b, pblk, agg, E, nTiles);
    k_fold_st<<<1, 64, 0, stream>>>(g1b, bt1b, pblk, fE, 256, 320, 832, 896);
    k_x1     <<<gElem, 256, 0, stream>>>(agg, pblk, x1b, NF);
    k_pass3  <<<gPass, 256, 0, stream>>>(x1b, eord, esrc, edst, W2, b2, pblk, agg, E, nTiles);
    k_fold_st<<<1, 64, 0, stream>>>(g2, bt2, pblk, fE, 384, 448, 960, 1024);
    k_fuse   <<<(N + FUSE_NODES - 1)/FUSE_NODES, 256, 0, stream>>>(agg, x1b, batch, pblk, N);
    k_out    <<<32, 256, 0, stream>>>(pblk, (float*)d_out);
}